// Round 1
// baseline (1184.186 us; speedup 1.0000x reference)
//
#include <hip/hip_runtime.h>

// Problem constants
#define NB    32
#define CDIM  256
#define HWSZ  4096                 // 64*64
#define NPOS  (NB*HWSZ)            // 131072
#define KCODES 1024
#define QELEMS ((size_t)NB*CDIM*HWSZ)   // 33554432
#define IDX_OFF QELEMS
#define DIFF_OFF (QELEMS + NPOS)

// ---------------------------------------------------------------------------
// Kernel E2: e2[k] = sum_c embed[k][c]^2, stashed into d_out[0..1024)
// (quantize region scratch — consumed by kernel A, overwritten by kernel B).
// Also zeroes the diff accumulator at d_out[DIFF_OFF].
// ---------------------------------------------------------------------------
__global__ __launch_bounds__(64) void vq_e2_kernel(const float* __restrict__ embed,
                                                   float* __restrict__ out) {
    int k = blockIdx.x;
    int lane = threadIdx.x;
    const float4 v = *reinterpret_cast<const float4*>(embed + (size_t)k * CDIM + lane * 4);
    float s = v.x * v.x + v.y * v.y + v.z * v.z + v.w * v.w;
    #pragma unroll
    for (int m = 1; m < 64; m <<= 1) s += __shfl_xor(s, m, 64);
    if (lane == 0) out[k] = s;
    if (k == 0 && lane == 0) out[DIFF_OFF] = 0.0f;
}

// ---------------------------------------------------------------------------
// Kernel A: fused distance GEMM + argmin.
// Block = 256 threads, 64 positions x all 1024 codes (N-chunks of 128, K=32).
// Thread (ty,tx): 4 positions x 8 codes fp32 accumulators.
// Writes argmin index per position AS FLOAT to d_out[IDX_OFF + p].
// ---------------------------------------------------------------------------
#define BM 64
#define BN 128
#define BK 32

__global__ __launch_bounds__(256) void vq_argmin_kernel(const float* __restrict__ x,
                                                        const float* __restrict__ embed,
                                                        float* __restrict__ out) {
    __shared__ float xs[BK][BM];   // 8 KB
    __shared__ float es[BK][BN];   // 16 KB (transposed: [k][code])

    const float* __restrict__ e2 = out;              // stash from vq_e2_kernel
    float* __restrict__ idx_out = out + IDX_OFF;

    const int tid = threadIdx.x;
    const int tx = tid & 15;   // code group
    const int ty = tid >> 4;   // position group (0..15)
    const int b = blockIdx.x;  // 0..2047
    const int n = b >> 6;
    const int hw0 = (b & 63) << 6;
    const float* __restrict__ xbase = x + (size_t)n * (CDIM * HWSZ) + hw0;

    float best[4];
    int   bidx[4];
    float x2[4] = {0.f, 0.f, 0.f, 0.f};
    #pragma unroll
    for (int i = 0; i < 4; ++i) { best[i] = 3.4e38f; bidx[i] = 0; }

    for (int nc = 0; nc < KCODES / BN; ++nc) {
        const int code0 = nc * BN;
        float acc[4][8];
        #pragma unroll
        for (int i = 0; i < 4; ++i)
            #pragma unroll
            for (int j = 0; j < 8; ++j) acc[i][j] = 0.f;

        for (int kc = 0; kc < CDIM / BK; ++kc) {
            const int k0 = kc * BK;
            __syncthreads();
            // stage x tile: 32 x 64 floats, coalesced float4
            #pragma unroll
            for (int i = 0; i < 2; ++i) {
                int f = i * 256 + tid;
                int kk = f >> 4;
                int j4 = (f & 15) << 2;
                *reinterpret_cast<float4*>(&xs[kk][j4]) =
                    *reinterpret_cast<const float4*>(xbase + (size_t)(k0 + kk) * HWSZ + j4);
            }
            // stage e tile transposed: es[kk][code] = embed[code0+code][k0+kk]
            #pragma unroll
            for (int i = 0; i < 4; ++i) {
                int f = i * 256 + tid;
                int j = f & 127;     // code within chunk
                int cc4 = f >> 7;    // channel quad 0..7
                float4 ev = *reinterpret_cast<const float4*>(
                    embed + (size_t)(code0 + j) * CDIM + k0 + (cc4 << 2));
                es[cc4 * 4 + 0][j] = ev.x;
                es[cc4 * 4 + 1][j] = ev.y;
                es[cc4 * 4 + 2][j] = ev.z;
                es[cc4 * 4 + 3][j] = ev.w;
            }
            __syncthreads();

            #pragma unroll
            for (int kk = 0; kk < BK; ++kk) {
                float4 xv = *reinterpret_cast<const float4*>(&xs[kk][ty * 4]);
                float4 e0 = *reinterpret_cast<const float4*>(&es[kk][tx * 4]);
                float4 e1 = *reinterpret_cast<const float4*>(&es[kk][64 + tx * 4]);
                float xa[4] = {xv.x, xv.y, xv.z, xv.w};
                float eb[8] = {e0.x, e0.y, e0.z, e0.w, e1.x, e1.y, e1.z, e1.w};
                #pragma unroll
                for (int i = 0; i < 4; ++i) {
                    #pragma unroll
                    for (int j = 0; j < 8; ++j)
                        acc[i][j] = fmaf(xa[i], eb[j], acc[i][j]);
                }
                if (nc == 0) {
                    #pragma unroll
                    for (int i = 0; i < 4; ++i) x2[i] = fmaf(xa[i], xa[i], x2[i]);
                }
            }
        }

        // scores + running argmin for this N-chunk
        #pragma unroll
        for (int j = 0; j < 8; ++j) {
            const int code = code0 + ((j < 4) ? (tx * 4 + j) : (64 + tx * 4 + (j - 4)));
            const float ec = e2[code];
            #pragma unroll
            for (int i = 0; i < 4; ++i) {
                // match reference op order: (x2 - 2*dot) + e2
                float s = (x2[i] - 2.0f * acc[i][j]) + ec;
                if (s < best[i] || (s == best[i] && code < bidx[i])) {
                    best[i] = s;
                    bidx[i] = code;
                }
            }
        }
    }

    // cross-lane combine over the 16 tx-lanes (same ty group within wave)
    #pragma unroll
    for (int m = 1; m < 16; m <<= 1) {
        #pragma unroll
        for (int i = 0; i < 4; ++i) {
            float ov = __shfl_xor(best[i], m, 64);
            int   oi = __shfl_xor(bidx[i], m, 64);
            if (ov < best[i] || (ov == best[i] && oi < bidx[i])) {
                best[i] = ov;
                bidx[i] = oi;
            }
        }
    }
    if (tx == 0) {
        #pragma unroll
        for (int i = 0; i < 4; ++i) {
            int p = b * BM + ty * 4 + i;
            idx_out[p] = (float)bidx[i];
        }
    }
}

// ---------------------------------------------------------------------------
// Kernel B: gather quantize = embed[idx], write NCHW, accumulate MSE diff.
// 512 blocks x 256 threads; thread <-> one position (coalesced over hw).
// ---------------------------------------------------------------------------
__global__ __launch_bounds__(256) void vq_gather_kernel(const float* __restrict__ x,
                                                        const float* __restrict__ embed,
                                                        float* __restrict__ out) {
    const int tid = threadIdx.x;
    const int p = blockIdx.x * 256 + tid;
    const int n = p >> 12;       // /4096
    const int hw = p & 4095;
    const int idx = (int)out[IDX_OFF + p];
    const float* __restrict__ erow = embed + (size_t)idx * CDIM;
    const float* __restrict__ xp = x + (size_t)n * (CDIM * HWSZ) + hw;
    float* __restrict__ op = out + (size_t)n * (CDIM * HWSZ) + hw;

    float local = 0.f;
    #pragma unroll 4
    for (int c = 0; c < CDIM; ++c) {
        float q = erow[c];
        float xv = xp[(size_t)c * HWSZ];
        op[(size_t)c * HWSZ] = q;
        float d = q - xv;
        local = fmaf(d, d, local);
    }

    // block reduction
    #pragma unroll
    for (int m = 1; m < 64; m <<= 1) local += __shfl_xor(local, m, 64);
    __shared__ float red[4];
    const int lane = tid & 63;
    const int w = tid >> 6;
    if (lane == 0) red[w] = local;
    __syncthreads();
    if (tid == 0) {
        float s = red[0] + red[1] + red[2] + red[3];
        atomicAdd(out + DIFF_OFF, s * (1.0f / 33554432.0f));
    }
}

extern "C" void kernel_launch(void* const* d_in, const int* in_sizes, int n_in,
                              void* d_out, int out_size, void* d_ws, size_t ws_size,
                              hipStream_t stream) {
    const float* x = (const float*)d_in[0];
    const float* embed = (const float*)d_in[1];
    float* out = (float*)d_out;

    vq_e2_kernel<<<KCODES, 64, 0, stream>>>(embed, out);
    vq_argmin_kernel<<<NPOS / BM, 256, 0, stream>>>(x, embed, out);
    vq_gather_kernel<<<NPOS / 256, 256, 0, stream>>>(x, embed, out);
}

// Round 3
// 466.208 us; speedup vs baseline: 2.5400x; 2.5400x over previous
//
#include <hip/hip_runtime.h>

// Problem constants
#define NB    32
#define CDIM  256
#define HWSZ  4096                 // 64*64
#define NPOS  (NB*HWSZ)            // 131072
#define KCODES 1024
#define QELEMS ((size_t)NB*CDIM*HWSZ)   // 33554432
#define IDX_OFF QELEMS
#define DIFF_OFF (QELEMS + NPOS)
#define E2F_OFF 393216             // float offset of e2 table in d_out scratch
// fp16 codebook ebuf occupies halfs [0 .. 1024*768) = floats [0 .. 393216)

typedef _Float16 f16x8 __attribute__((ext_vector_type(8)));
typedef float    f32x4 __attribute__((ext_vector_type(4)));

static __device__ inline unsigned short f2h(float f) {
    _Float16 h = (_Float16)f;
    return __builtin_bit_cast(unsigned short, h);
}

// ---------------------------------------------------------------------------
// prep_embed: per code k, write fp16 [eh(256) | el'(256) | eh(256)] to ebuf,
// e2[k] (fp32) to e2buf; zero the diff accumulator.
// ---------------------------------------------------------------------------
__global__ __launch_bounds__(64) void vq_prep_embed(const float* __restrict__ embed,
                                                    float* __restrict__ out) {
    const int k = blockIdx.x;
    const int lane = threadIdx.x;
    const float4 v = *reinterpret_cast<const float4*>(embed + (size_t)k * CDIM + lane * 4);

    unsigned short* __restrict__ ebuf = (unsigned short*)out;

    _Float16 h0 = (_Float16)v.x, h1 = (_Float16)v.y, h2 = (_Float16)v.z, h3 = (_Float16)v.w;
    float r0 = (v.x - (float)h0) * 2048.0f;
    float r1 = (v.y - (float)h1) * 2048.0f;
    float r2 = (v.z - (float)h2) * 2048.0f;
    float r3 = (v.w - (float)h3) * 2048.0f;

    ushort4 hv = { __builtin_bit_cast(unsigned short, h0), __builtin_bit_cast(unsigned short, h1),
                   __builtin_bit_cast(unsigned short, h2), __builtin_bit_cast(unsigned short, h3) };
    ushort4 lv = { f2h(r0), f2h(r1), f2h(r2), f2h(r3) };

    const size_t base = (size_t)k * 768;
    *reinterpret_cast<ushort4*>(ebuf + base + lane * 4)       = hv;   // eh
    *reinterpret_cast<ushort4*>(ebuf + base + 256 + lane * 4) = lv;   // el'
    *reinterpret_cast<ushort4*>(ebuf + base + 512 + lane * 4) = hv;   // eh copy

    float s = v.x * v.x + v.y * v.y + v.z * v.z + v.w * v.w;
    #pragma unroll
    for (int m = 1; m < 64; m <<= 1) s += __shfl_xor(s, m, 64);
    if (lane == 0) out[E2F_OFF + k] = s;
    if (k == 0 && lane == 0) out[DIFF_OFF] = 0.0f;
}

// ---------------------------------------------------------------------------
// stage1: fused fp16-split MFMA distance + argmin.
// Block: 64 positions x 1024 codes. 4 waves as 2(pos-half wy) x 2(code-half wx).
// A LDS [64 pos][512 k] fp16 (xh|xl'), XOR-swizzled.  B LDS [128 codes][64 k].
// K' = 768 sweep: k'<256 -> accA (xh*eh); k'>=256 -> accB (cross terms, /2048).
// Cross-wave (wx) argmin merge through LDS before writing indices.
// ---------------------------------------------------------------------------
__global__ __launch_bounds__(256, 2) void vq_stage1(const float* __restrict__ x,
                                                    float* __restrict__ out) {
    __shared__ __align__(16) unsigned char lds[81920];   // 64KB A + 16KB B = 80 KiB

    const unsigned short* __restrict__ ebuf  = (const unsigned short*)out;
    const float* __restrict__ e2buf = out + E2F_OFF;
    float* __restrict__ idx_out = out + IDX_OFF;

    const int t    = threadIdx.x;
    const int lane = t & 63;
    const int col  = lane & 15;
    const int kgrp = lane >> 4;
    const int widx = t >> 6;
    const int wy   = widx >> 1;          // position half (0..1)
    const int wx   = widx & 1;           // code half (0..1)

    const int pos0 = blockIdx.x * 64;
    const int n    = pos0 >> 12;
    const int hw0  = pos0 & 4095;
    const float* __restrict__ xbase = x + (size_t)n * (CDIM * HWSZ) + hw0;

    // ---- A staging: x fp32 -> fp16 hi/lo into LDS [64][512], + x2 partials
    {
        const int i = t & 63;            // position lane (coalesced)
        const int g = t >> 6;            // channel group
        unsigned char* arow = lds + i * 1024;
        const int sw = (i & 7) << 4;
        float x2part = 0.f;
        #pragma unroll
        for (int it = 0; it < 16; ++it) {
            const int cb = it * 16 + g * 4;
            float v0 = xbase[(size_t)(cb + 0) * HWSZ + i];
            float v1 = xbase[(size_t)(cb + 1) * HWSZ + i];
            float v2 = xbase[(size_t)(cb + 2) * HWSZ + i];
            float v3 = xbase[(size_t)(cb + 3) * HWSZ + i];
            x2part += v0 * v0 + v1 * v1 + v2 * v2 + v3 * v3;
            _Float16 h0 = (_Float16)v0, h1 = (_Float16)v1, h2 = (_Float16)v2, h3 = (_Float16)v3;
            ushort4 hv = { __builtin_bit_cast(unsigned short, h0), __builtin_bit_cast(unsigned short, h1),
                           __builtin_bit_cast(unsigned short, h2), __builtin_bit_cast(unsigned short, h3) };
            ushort4 lv = { f2h((v0 - (float)h0) * 2048.0f), f2h((v1 - (float)h1) * 2048.0f),
                           f2h((v2 - (float)h2) * 2048.0f), f2h((v3 - (float)h3) * 2048.0f) };
            *reinterpret_cast<ushort4*>(arow + ((cb * 2) ^ sw))       = hv;  // xh
            *reinterpret_cast<ushort4*>(arow + ((512 + cb * 2) ^ sw)) = lv;  // xl'
        }
        ((float*)(lds + 65536))[g * 64 + i] = x2part;
    }
    __syncthreads();

    // gather x2 for this thread's 8 accumulator rows
    float x2r[8];
    {
        const float* x2p = (const float*)(lds + 65536);
        #pragma unroll
        for (int rg = 0; rg < 2; ++rg)
            #pragma unroll
            for (int reg = 0; reg < 4; ++reg) {
                const int row = wy * 32 + rg * 16 + kgrp * 4 + reg;
                x2r[rg * 4 + reg] = x2p[row] + x2p[64 + row] + x2p[128 + row] + x2p[192 + row];
            }
    }

    float bestv[8];
    int   besti[8];
    #pragma unroll
    for (int sl = 0; sl < 8; ++sl) { bestv[sl] = 3.4e38f; besti[sl] = 0; }

    f32x4 accA[2][4], accB[2][4];
    const f32x4 zero4 = {0.f, 0.f, 0.f, 0.f};

    for (int ss = 0; ss < 96; ++ss) {
        const int cc = ss / 12;
        const int kq = ss - cc * 12;     // 0..11 (K'=64 chunk)
        const int code0 = cc * 128;
        const int k0h = kq * 64;

        if (kq == 0) {
            #pragma unroll
            for (int rg = 0; rg < 2; ++rg)
                #pragma unroll
                for (int cf = 0; cf < 4; ++cf) { accA[rg][cf] = zero4; accB[rg][cf] = zero4; }
        }

        __syncthreads();   // everyone done reading B (or x2 area) from previous step
        // ---- stage B tile [128 codes][64 halfs] swizzled
        #pragma unroll
        for (int ii = 0; ii < 4; ++ii) {
            const int chunk = ii * 256 + t;       // 0..1023 16B-chunks
            const int code  = chunk >> 3;
            const int slot  = chunk & 7;
            const uint4 v = *reinterpret_cast<const uint4*>(
                ebuf + (size_t)(code0 + code) * 768 + k0h + slot * 8);
            const int phys = 65536 + ((code * 128 + slot * 16) ^ ((code & 7) << 4));
            *reinterpret_cast<uint4*>(lds + phys) = v;
        }
        __syncthreads();

        // ---- compute: 2 MFMA k-steps of K=32
        const int mbase = (kq < 4) ? k0h : (k0h - 256);   // A column base (xh | xl')
        #pragma unroll
        for (int kk = 0; kk < 2; ++kk) {
            f16x8 a[2], b[4];
            #pragma unroll
            for (int rg = 0; rg < 2; ++rg) {
                const int row = wy * 32 + rg * 16 + col;
                const int byte = row * 1024 + ((mbase + kk * 32 + kgrp * 8) << 1);
                a[rg] = *reinterpret_cast<const f16x8*>(lds + (byte ^ ((row & 7) << 4)));
            }
            #pragma unroll
            for (int cf = 0; cf < 4; ++cf) {
                const int brow = wx * 64 + cf * 16 + col;
                const int byte = brow * 128 + kk * 64 + kgrp * 16;
                b[cf] = *reinterpret_cast<const f16x8*>(lds + 65536 + (byte ^ ((brow & 7) << 4)));
            }
            if (kq < 4) {
                #pragma unroll
                for (int rg = 0; rg < 2; ++rg)
                    #pragma unroll
                    for (int cf = 0; cf < 4; ++cf)
                        accA[rg][cf] = __builtin_amdgcn_mfma_f32_16x16x32_f16(
                            a[rg], b[cf], accA[rg][cf], 0, 0, 0);
            } else {
                #pragma unroll
                for (int rg = 0; rg < 2; ++rg)
                    #pragma unroll
                    for (int cf = 0; cf < 4; ++cf)
                        accB[rg][cf] = __builtin_amdgcn_mfma_f32_16x16x32_f16(
                            a[rg], b[cf], accB[rg][cf], 0, 0, 0);
            }
        }

        // ---- epilogue per code-chunk: scores + running argmin
        if (kq == 11) {
            float e2v[4];
            #pragma unroll
            for (int cf = 0; cf < 4; ++cf)
                e2v[cf] = e2buf[code0 + wx * 64 + cf * 16 + col];
            #pragma unroll
            for (int cf = 0; cf < 4; ++cf) {
                const int code = code0 + wx * 64 + cf * 16 + col;
                #pragma unroll
                for (int rg = 0; rg < 2; ++rg) {
                    #pragma unroll
                    for (int reg = 0; reg < 4; ++reg) {
                        const float dot = accA[rg][cf][reg] + accB[rg][cf][reg] * (1.0f / 2048.0f);
                        const float s = (x2r[rg * 4 + reg] - 2.0f * dot) + e2v[cf];
                        const int sl = rg * 4 + reg;
                        if (s < bestv[sl]) { bestv[sl] = s; besti[sl] = code; }
                    }
                }
            }
        }
    }

    // ---- cross-lane argmin merge over the 16 code-columns (within wave)
    #pragma unroll
    for (int sl = 0; sl < 8; ++sl) {
        #pragma unroll
        for (int m = 1; m < 16; m <<= 1) {
            float ov = __shfl_xor(bestv[sl], m, 64);
            int   oi = __shfl_xor(besti[sl], m, 64);
            if (ov < bestv[sl] || (ov == bestv[sl] && oi < besti[sl])) {
                bestv[sl] = ov; besti[sl] = oi;
            }
        }
    }

    // ---- cross-wave merge: wx=1 deposits, wx=0 merges + writes
    __syncthreads();                     // all waves done with LDS tile reads
    {
        float* mv = (float*)lds;         // 64 floats
        int*   mi = (int*)(lds + 256);   // 64 ints
        if (wx == 1 && col == 0) {
            #pragma unroll
            for (int rg = 0; rg < 2; ++rg)
                #pragma unroll
                for (int reg = 0; reg < 4; ++reg) {
                    const int p = wy * 32 + rg * 16 + kgrp * 4 + reg;
                    mv[p] = bestv[rg * 4 + reg];
                    mi[p] = besti[rg * 4 + reg];
                }
        }
        __syncthreads();
        if (wx == 0 && col == 0) {
            #pragma unroll
            for (int rg = 0; rg < 2; ++rg)
                #pragma unroll
                for (int reg = 0; reg < 4; ++reg) {
                    const int sl = rg * 4 + reg;
                    const int p = wy * 32 + rg * 16 + kgrp * 4 + reg;
                    const float ov = mv[p];
                    const int   oi = mi[p];
                    if (ov < bestv[sl] || (ov == bestv[sl] && oi < besti[sl])) {
                        bestv[sl] = ov; besti[sl] = oi;
                    }
                    idx_out[pos0 + p] = (float)besti[sl];
                }
        }
    }
}

// ---------------------------------------------------------------------------
// gather: quantize = embed[idx] (NCHW), accumulate MSE diff.  (round-1 proven)
// ---------------------------------------------------------------------------
__global__ __launch_bounds__(256) void vq_gather_kernel(const float* __restrict__ x,
                                                        const float* __restrict__ embed,
                                                        float* __restrict__ out) {
    const int tid = threadIdx.x;
    const int p = blockIdx.x * 256 + tid;
    const int n = p >> 12;
    const int hw = p & 4095;
    const int idx = (int)out[IDX_OFF + p];
    const float* __restrict__ erow = embed + (size_t)idx * CDIM;
    const float* __restrict__ xp = x + (size_t)n * (CDIM * HWSZ) + hw;
    float* __restrict__ op = out + (size_t)n * (CDIM * HWSZ) + hw;

    float local = 0.f;
    #pragma unroll 4
    for (int c = 0; c < CDIM; ++c) {
        float q = erow[c];
        float xv = xp[(size_t)c * HWSZ];
        op[(size_t)c * HWSZ] = q;
        float d = q - xv;
        local = fmaf(d, d, local);
    }

    #pragma unroll
    for (int m = 1; m < 64; m <<= 1) local += __shfl_xor(local, m, 64);
    __shared__ float red[4];
    const int lane = tid & 63;
    const int w = tid >> 6;
    if (lane == 0) red[w] = local;
    __syncthreads();
    if (tid == 0) {
        float s = red[0] + red[1] + red[2] + red[3];
        atomicAdd(out + DIFF_OFF, s * (1.0f / 33554432.0f));
    }
}

extern "C" void kernel_launch(void* const* d_in, const int* in_sizes, int n_in,
                              void* d_out, int out_size, void* d_ws, size_t ws_size,
                              hipStream_t stream) {
    const float* x = (const float*)d_in[0];
    const float* embed = (const float*)d_in[1];
    float* out = (float*)d_out;

    vq_prep_embed<<<KCODES, 64, 0, stream>>>(embed, out);
    vq_stage1<<<NPOS / 64, 256, 0, stream>>>(x, out);
    vq_gather_kernel<<<NPOS / 256, 256, 0, stream>>>(x, embed, out);
}

// Round 4
// 362.374 us; speedup vs baseline: 3.2679x; 1.2865x over previous
//
#include <hip/hip_runtime.h>

// Problem constants
#define NB    32
#define CDIM  256
#define HWSZ  4096                 // 64*64
#define NPOS  (NB*HWSZ)            // 131072
#define KCODES 1024
#define QELEMS ((size_t)NB*CDIM*HWSZ)   // 33554432
#define IDX_OFF QELEMS
#define DIFF_OFF (QELEMS + NPOS)
#define E2F_OFF 393216             // float offset of e2 table in d_out scratch
// Pre-swizzled fp16 codebook tiles occupy bytes [0 .. 48*32768) = floats [0..393216)

typedef _Float16       f16x8  __attribute__((ext_vector_type(8)));
typedef float          f32x4  __attribute__((ext_vector_type(4)));
typedef unsigned short u16x8  __attribute__((ext_vector_type(8)));

static __device__ inline unsigned short f2h(float f) {
    _Float16 h = (_Float16)f;
    return __builtin_bit_cast(unsigned short, h);
}

// ---------------------------------------------------------------------------
// prep_embed: build the PRE-SWIZZLED fp16 codebook in d_out scratch.
// Logical layout per code: k' in [0,768) = [eh(256) | el'(256) | eh(256)].
// Tile (cc,kq) = 32KB: codes cc*256..+256, k' slice kq*64..+64.
// Physical within tile: code*128 + ((slot ^ (code&7))<<4) + sub*2  (slot=16B).
// Also e2[k] -> out[E2F_OFF+k], zero diff accumulator.
// ---------------------------------------------------------------------------
__global__ __launch_bounds__(64) void vq_prep_embed(const float* __restrict__ embed,
                                                    float* __restrict__ out) {
    const int k = blockIdx.x;
    const int lane = threadIdx.x;
    const float4 v = *reinterpret_cast<const float4*>(embed + (size_t)k * CDIM + lane * 4);

    unsigned char* __restrict__ ebuf = (unsigned char*)out;

    _Float16 h0 = (_Float16)v.x, h1 = (_Float16)v.y, h2 = (_Float16)v.z, h3 = (_Float16)v.w;
    ushort4 hv = { __builtin_bit_cast(unsigned short, h0), __builtin_bit_cast(unsigned short, h1),
                   __builtin_bit_cast(unsigned short, h2), __builtin_bit_cast(unsigned short, h3) };
    ushort4 lv = { f2h((v.x - (float)h0) * 2048.0f), f2h((v.y - (float)h1) * 2048.0f),
                   f2h((v.z - (float)h2) * 2048.0f), f2h((v.w - (float)h3) * 2048.0f) };

    const int cc = k >> 8;
    const int cr = k & 255;
    const int sw = cr & 7;
    auto put = [&](int kp, ushort4 val) {
        const int kq = kp >> 6, off = kp & 63, slot = off >> 3, sub = off & 7;
        const size_t byte = (size_t)(cc * 12 + kq) * 32768 + (size_t)cr * 128
                          + (size_t)(((slot ^ sw) << 4) + sub * 2);
        *reinterpret_cast<ushort4*>(ebuf + byte) = val;
    };
    put(lane * 4, hv);          // eh
    put(256 + lane * 4, lv);    // el'
    put(512 + lane * 4, hv);    // eh copy

    float s = v.x * v.x + v.y * v.y + v.z * v.z + v.w * v.w;
    #pragma unroll
    for (int m = 1; m < 64; m <<= 1) s += __shfl_xor(s, m, 64);
    if (lane == 0) out[E2F_OFF + k] = s;
    if (k == 0 && lane == 0) out[DIFF_OFF] = 0.0f;
}

// ---------------------------------------------------------------------------
// stage1: fused fp16-split MFMA distance + argmin + diff.
// 512 threads = 8 waves: wy in {0,1} (32 pos), wx in {0..3} (64 codes of tile).
// A LDS [64 pos][512 k] fp16 (xh|xl'), swizzled, static after prologue.
// B LDS double-buffered 2x32KB tiles, staged via global_load_lds (pre-swizzled
// source => fully linear copy). One __syncthreads per step (counted-drain).
// diff accumulated from bestv (== min distance) — gather no longer reads x.
// ---------------------------------------------------------------------------
#define ABYTES 65536
#define BBYTES 32768
#define B0OFF  ABYTES
#define SCROFF (ABYTES + 2*BBYTES)    // 131072

__global__ __launch_bounds__(512, 2) void vq_stage1(const float* __restrict__ x,
                                                    float* __restrict__ out) {
    __shared__ __align__(16) unsigned char lds[SCROFF + 2048];

    const unsigned char* __restrict__ ebuf = (const unsigned char*)out;
    const float* __restrict__ e2buf = out + E2F_OFF;
    float* __restrict__ idx_out = out + IDX_OFF;

    const int t    = threadIdx.x;
    const int lane = t & 63;
    const int col  = lane & 15;
    const int kgrp = lane >> 4;
    const int widx = t >> 6;           // 0..7
    const int wy   = widx >> 2;        // 0..1 : position half
    const int wx   = widx & 3;         // 0..3 : 64-code group within 256-tile

    const int pos0 = blockIdx.x * 64;
    const int n    = pos0 >> 12;
    const int hw0  = pos0 & 4095;
    const float* __restrict__ xbase = x + (size_t)n * (CDIM * HWSZ) + hw0;

    // ---- A staging: x fp32 -> fp16 hi/lo, [64][512] halfs swizzled; x2 partials
    {
        const int i = t & 63;          // position (coalesced)
        const int g = t >> 6;          // channel group 0..7 (32 ch each)
        unsigned char* arow = lds + i * 1024;
        const int sw = (i & 7) << 4;
        float x2p = 0.f;
        #pragma unroll
        for (int it = 0; it < 4; ++it) {
            const int cb = g * 32 + it * 8;
            u16x8 hv, lv;
            #pragma unroll
            for (int j = 0; j < 8; ++j) {
                float vv = xbase[(size_t)(cb + j) * HWSZ + i];
                x2p = fmaf(vv, vv, x2p);
                _Float16 hh = (_Float16)vv;
                hv[j] = __builtin_bit_cast(unsigned short, hh);
                lv[j] = f2h((vv - (float)hh) * 2048.0f);
            }
            *reinterpret_cast<u16x8*>(arow + ((cb * 2) ^ sw))       = hv;   // xh
            *reinterpret_cast<u16x8*>(arow + ((512 + cb * 2) ^ sw)) = lv;   // xl'
        }
        ((float*)(lds + SCROFF))[g * 64 + i] = x2p;
    }

    // ---- async B staging helper (linear copy: source is pre-swizzled)
    auto stage = [&](int tile, int buf) {
        const unsigned char* src = ebuf + (size_t)tile * BBYTES;
        unsigned char* dst = lds + B0OFF + buf * BBYTES;
        #pragma unroll
        for (int ii = 0; ii < 4; ++ii) {
            const int chunk = (widx * 4 + ii) * 1024;
            __builtin_amdgcn_global_load_lds(
                (const __attribute__((address_space(1))) unsigned int*)(src + chunk + lane * 16),
                (__attribute__((address_space(3))) unsigned int*)(dst + chunk),
                16, 0, 0);
        }
    };

    stage(0, 0);

    // preload e2 for this thread's 16 codes
    float e2pre[16];
    #pragma unroll
    for (int cc = 0; cc < 4; ++cc)
        #pragma unroll
        for (int cf = 0; cf < 4; ++cf)
            e2pre[cc * 4 + cf] = e2buf[cc * 256 + wx * 64 + cf * 16 + col];

    __syncthreads();   // A + x2 + tile0 all resident

    // gather x2 for this thread's 8 output rows
    float x2r[8];
    {
        const float* x2p = (const float*)(lds + SCROFF);
        #pragma unroll
        for (int rg = 0; rg < 2; ++rg)
            #pragma unroll
            for (int reg = 0; reg < 4; ++reg) {
                const int row = wy * 32 + rg * 16 + kgrp * 4 + reg;
                float s = 0.f;
                #pragma unroll
                for (int g = 0; g < 8; ++g) s += x2p[g * 64 + row];
                x2r[rg * 4 + reg] = s;
            }
    }

    float bestv[8];
    int   besti[8];
    #pragma unroll
    for (int sl = 0; sl < 8; ++sl) { bestv[sl] = 3.4e38f; besti[sl] = 0; }

    const f32x4 zero4 = {0.f, 0.f, 0.f, 0.f};
    int cur = 0, tile = 0;

    for (int cc = 0; cc < 4; ++cc) {
        f32x4 accA[2][4], accB[2][4];
        #pragma unroll
        for (int rg = 0; rg < 2; ++rg)
            #pragma unroll
            for (int cf = 0; cf < 4; ++cf) { accA[rg][cf] = zero4; accB[rg][cf] = zero4; }

        for (int kq = 0; kq < 12; ++kq, ++tile) {
            if (tile + 1 < 48) stage(tile + 1, cur ^ 1);   // prefetch next tile

            const unsigned char* bbase = lds + B0OFF + cur * BBYTES;
            const int mbase = (kq < 4) ? kq * 64 : kq * 64 - 256;   // A col (halfs)

            __builtin_amdgcn_s_setprio(1);
            #pragma unroll
            for (int kk = 0; kk < 2; ++kk) {
                f16x8 a[2], b[4];
                #pragma unroll
                for (int rg = 0; rg < 2; ++rg) {
                    const int row = wy * 32 + rg * 16 + col;
                    const int byte = row * 1024 + ((mbase + kk * 32 + kgrp * 8) << 1);
                    a[rg] = *reinterpret_cast<const f16x8*>(lds + (byte ^ ((row & 7) << 4)));
                }
                #pragma unroll
                for (int cf = 0; cf < 4; ++cf) {
                    const int brow = wx * 64 + cf * 16 + col;
                    const int byte = brow * 128 + kk * 64 + kgrp * 16;
                    b[cf] = *reinterpret_cast<const f16x8*>(bbase + (byte ^ ((brow & 7) << 4)));
                }
                if (kq < 4) {
                    #pragma unroll
                    for (int rg = 0; rg < 2; ++rg)
                        #pragma unroll
                        for (int cf = 0; cf < 4; ++cf)
                            accA[rg][cf] = __builtin_amdgcn_mfma_f32_16x16x32_f16(
                                a[rg], b[cf], accA[rg][cf], 0, 0, 0);
                } else {
                    #pragma unroll
                    for (int rg = 0; rg < 2; ++rg)
                        #pragma unroll
                        for (int cf = 0; cf < 4; ++cf)
                            accB[rg][cf] = __builtin_amdgcn_mfma_f32_16x16x32_f16(
                                a[rg], b[cf], accB[rg][cf], 0, 0, 0);
                }
            }
            __builtin_amdgcn_s_setprio(0);

            __syncthreads();   // drains this step's prefetch (vmcnt 0) + LDS reads
            cur ^= 1;
        }

        // ---- epilogue for this 256-code chunk: scores + running argmin
        #pragma unroll
        for (int cf = 0; cf < 4; ++cf) {
            const int code = cc * 256 + wx * 64 + cf * 16 + col;
            const float ec = e2pre[cc * 4 + cf];
            #pragma unroll
            for (int rg = 0; rg < 2; ++rg)
                #pragma unroll
                for (int reg = 0; reg < 4; ++reg) {
                    const float dot = accA[rg][cf][reg] + accB[rg][cf][reg] * (1.0f / 2048.0f);
                    const float s = (x2r[rg * 4 + reg] - 2.0f * dot) + ec;
                    const int sl = rg * 4 + reg;
                    if (s < bestv[sl]) { bestv[sl] = s; besti[sl] = code; }
                }
        }
    }

    // ---- in-wave argmin merge over the 16 code-columns
    #pragma unroll
    for (int sl = 0; sl < 8; ++sl) {
        #pragma unroll
        for (int m = 1; m < 16; m <<= 1) {
            float ov = __shfl_xor(bestv[sl], m, 64);
            int   oi = __shfl_xor(besti[sl], m, 64);
            if (ov < bestv[sl] || (ov == bestv[sl] && oi < besti[sl])) {
                bestv[sl] = ov; besti[sl] = oi;
            }
        }
    }

    // ---- cross-wave (wx) merge through LDS; wx=0 writes idx + diff partial
    {
        float* mv = (float*)(lds + SCROFF);
        int*   mi = (int*)(lds + SCROFF + 1024);
        if (wx != 0 && col == 0) {
            #pragma unroll
            for (int rg = 0; rg < 2; ++rg)
                #pragma unroll
                for (int reg = 0; reg < 4; ++reg) {
                    const int p = wy * 32 + rg * 16 + kgrp * 4 + reg;
                    mv[(wx - 1) * 64 + p] = bestv[rg * 4 + reg];
                    mi[(wx - 1) * 64 + p] = besti[rg * 4 + reg];
                }
        }
        __syncthreads();
        if (wx == 0 && col == 0) {
            float dsum = 0.f;
            #pragma unroll
            for (int rg = 0; rg < 2; ++rg)
                #pragma unroll
                for (int reg = 0; reg < 4; ++reg) {
                    const int sl = rg * 4 + reg;
                    const int p = wy * 32 + rg * 16 + kgrp * 4 + reg;
                    #pragma unroll
                    for (int w = 0; w < 3; ++w) {
                        const float ov = mv[w * 64 + p];
                        const int   oi = mi[w * 64 + p];
                        if (ov < bestv[sl] || (ov == bestv[sl] && oi < besti[sl])) {
                            bestv[sl] = ov; besti[sl] = oi;
                        }
                    }
                    idx_out[pos0 + p] = (float)besti[sl];
                    dsum += bestv[sl];
                }
            atomicAdd(out + DIFF_OFF, dsum * (1.0f / 33554432.0f));
        }
    }
}

// ---------------------------------------------------------------------------
// gather: quantize = embed[idx] (NCHW). Write-only on the big buffer now
// (diff comes from stage1) — no x read.
// ---------------------------------------------------------------------------
__global__ __launch_bounds__(256) void vq_gather_kernel(const float* __restrict__ embed,
                                                        float* __restrict__ out) {
    const int tid = threadIdx.x;
    const int p = blockIdx.x * 256 + tid;
    const int n = p >> 12;
    const int hw = p & 4095;
    const int idx = (int)out[IDX_OFF + p];
    const float4* __restrict__ erow4 = reinterpret_cast<const float4*>(embed + (size_t)idx * CDIM);
    float* __restrict__ op = out + (size_t)n * (CDIM * HWSZ) + hw;

    #pragma unroll 8
    for (int c4 = 0; c4 < 64; ++c4) {
        const float4 e = erow4[c4];
        op[(size_t)(c4 * 4 + 0) * HWSZ] = e.x;
        op[(size_t)(c4 * 4 + 1) * HWSZ] = e.y;
        op[(size_t)(c4 * 4 + 2) * HWSZ] = e.z;
        op[(size_t)(c4 * 4 + 3) * HWSZ] = e.w;
    }
}

extern "C" void kernel_launch(void* const* d_in, const int* in_sizes, int n_in,
                              void* d_out, int out_size, void* d_ws, size_t ws_size,
                              hipStream_t stream) {
    const float* x = (const float*)d_in[0];
    const float* embed = (const float*)d_in[1];
    float* out = (float*)d_out;

    vq_prep_embed<<<KCODES, 64, 0, stream>>>(embed, out);
    vq_stage1<<<NPOS / 64, 512, 0, stream>>>(x, out);
    vq_gather_kernel<<<NPOS / 256, 256, 0, stream>>>(embed, out);
}